// Round 7
// baseline (376.981 us; speedup 1.0000x reference)
//
#include <hip/hip_runtime.h>
#include <hip/hip_bf16.h>

// ---------- helpers ----------
__device__ __forceinline__ float b2f(unsigned short u) {
  return __uint_as_float(((unsigned int)u) << 16);
}
__device__ __forceinline__ unsigned short f2b(float f) {
  unsigned int x = __float_as_uint(f);
  unsigned int r = x + 0x7FFFu + ((x >> 16) & 1u);  // RNE
  return (unsigned short)(r >> 16);
}
__device__ __forceinline__ unsigned int pack2(float lo, float hi) {
  return (unsigned int)f2b(lo) | ((unsigned int)f2b(hi) << 16);
}
// accumulate 8 bf16 (one uint4) into a[0..7]
__device__ __forceinline__ void acc8(float* a, uint4 p) {
  a[0] += __uint_as_float(p.x << 16); a[1] += __uint_as_float(p.x & 0xFFFF0000u);
  a[2] += __uint_as_float(p.y << 16); a[3] += __uint_as_float(p.y & 0xFFFF0000u);
  a[4] += __uint_as_float(p.z << 16); a[5] += __uint_as_float(p.z & 0xFFFF0000u);
  a[6] += __uint_as_float(p.w << 16); a[7] += __uint_as_float(p.w & 0xFFFF0000u);
}

typedef short bf16x8 __attribute__((ext_vector_type(8)));  // 8 bf16 = 4 VGPRs
typedef float f32x4 __attribute__((ext_vector_type(4)));

#define CHUNK 8192          // edges per P1/P3 block
#define NBUCKP 1024         // padded bucket count (bucket = dst >> 7, N <= 131072)

// ---------- dtype detection ----------
// hdr[0]: 0 = floats are bf16, 1 = floats are f32
// hdr[1]: 0 = edge_index int32, 1 = int64
__global__ void detect_kernel(const void* __restrict__ x_raw,
                              const void* __restrict__ idx_raw,
                              int* __restrict__ hdr) {
  int lane = threadIdx.x;  // 64 threads
  const unsigned short* xb = (const unsigned short*)x_raw;
  unsigned short u = xb[2 * lane];
  int e = (u >> 7) & 0xFF;
  bool sane = ((u & 0x7FFFu) == 0) || (e >= 107 && e <= 137);
  unsigned long long m = __ballot(sane);
  const int* ib = (const int*)idx_raw;
  int v = ib[2 * lane + 1];
  unsigned long long m2 = __ballot(v != 0);
  if (lane == 0) {
    hdr[0] = (__popcll(m) >= 32) ? 0 : 1;
    hdr[1] = (m2 == 0ull) ? 1 : 0;
  }
}

// ---------- weights -> bf16 (only when inputs are f32) ----------
__global__ void convert_w_kernel(const void* __restrict__ W1l, const void* __restrict__ W1r,
                                 const void* __restrict__ W2l, const void* __restrict__ W2r,
                                 const int* __restrict__ hdr,
                                 unsigned short* __restrict__ W1l_h, unsigned short* __restrict__ W1r_h,
                                 unsigned short* __restrict__ W2l_h, unsigned short* __restrict__ W2r_h) {
  if (hdr[0] == 0) return;  // bf16 inputs: GEMMs read raw W directly
  int i = blockIdx.x * blockDim.x + threadIdx.x;
  const float* s; unsigned short* d; int off;
  if (i < 8192)       { s = (const float*)W1l; d = W1l_h; off = i; }
  else if (i < 16384) { s = (const float*)W1r; d = W1r_h; off = i - 8192; }
  else if (i < 32768) { s = (const float*)W2l; d = W2l_h; off = i - 16384; }
  else if (i < 49152) { s = (const float*)W2r; d = W2r_h; off = i - 32768; }
  else return;
  d[off] = f2b(s[off]);
}

__global__ void convert_x_kernel(const void* __restrict__ x_raw,
                                 const int* __restrict__ hdr,
                                 unsigned short* __restrict__ xc, int n_elems) {
  if (hdr[0] == 0) return;  // bf16 inputs: consumers read x_raw directly
  int i = blockIdx.x * blockDim.x + threadIdx.x;
  if (i >= n_elems) return;
  xc[i] = f2b(((const float*)x_raw)[i]);
}

// ---------- P1: per-chunk bucket histogram (LDS atomics, uint4 idx reads) ----------
__global__ __launch_bounds__(256) void hist_chunks_kernel(
    const int* __restrict__ idx_raw, const int* __restrict__ hdr,
    int* __restrict__ H, int n_edges, int NC) {
  __shared__ int h[NBUCKP];
  for (int i = threadIdx.x; i < NBUCKP; i += 256) h[i] = 0;
  __syncthreads();
  const int c = blockIdx.x;
  const int base = c * CHUNK;
  const int lim = min(n_edges - base, CHUNK);
  if (hdr[1]) {
    const uint4* dp = (const uint4*)(idx_raw + 2 * (size_t)n_edges + 2 * (size_t)base);
    #pragma unroll
    for (int t = 0; t < CHUNK / 512; ++t) {
      int q = t * 256 + threadIdx.x;
      int e = 2 * q;
      if (e < lim) {
        uint4 v = dp[q];
        atomicAdd(&h[((int)v.x) >> 7], 1);
        if (e + 1 < lim) atomicAdd(&h[((int)v.z) >> 7], 1);
      }
    }
  } else {
    const uint4* dp = (const uint4*)(idx_raw + (size_t)n_edges + base);
    #pragma unroll
    for (int t = 0; t < CHUNK / 1024; ++t) {
      int q = t * 256 + threadIdx.x;
      int e = 4 * q;
      if (e < lim) {
        uint4 v = dp[q];
        atomicAdd(&h[((int)v.x) >> 7], 1);
        if (e + 1 < lim) atomicAdd(&h[((int)v.y) >> 7], 1);
        if (e + 2 < lim) atomicAdd(&h[((int)v.z) >> 7], 1);
        if (e + 3 < lim) atomicAdd(&h[((int)v.w) >> 7], 1);
      }
    }
  }
  __syncthreads();
  for (int i = threadIdx.x; i < NBUCKP; i += 256) H[(size_t)i * NC + c] = h[i];
}

// ---------- P2: flat exclusive scan of H ----------
__global__ __launch_bounds__(256) void gscan_sums_kernel(const int* __restrict__ arr,
                                                         int* __restrict__ blockSums, int n) {
  __shared__ int ws[4];
  int tid = threadIdx.x, lane = tid & 63, wid = tid >> 6;
  int base = blockIdx.x * 2048 + tid * 8;
  int s = 0;
  #pragma unroll
  for (int t = 0; t < 8; ++t) {
    int i = base + t;
    if (i < n) s += arr[i];
  }
  #pragma unroll
  for (int m = 1; m < 64; m <<= 1) s += __shfl_xor(s, m, 64);
  if (lane == 0) ws[wid] = s;
  __syncthreads();
  if (tid == 0) blockSums[blockIdx.x] = ws[0] + ws[1] + ws[2] + ws[3];
}

__global__ void gscan_offsets_kernel(const int* __restrict__ blockSums,
                                     int* __restrict__ blockOffs, int nb) {
  int lane = threadIdx.x;  // 64
  int carry = 0;
  for (int start = 0; start < nb; start += 64) {
    int i = start + lane;
    int v = (i < nb) ? blockSums[i] : 0;
    int isc = v;
    #pragma unroll
    for (int off = 1; off < 64; off <<= 1) {
      int t = __shfl_up(isc, off, 64);
      if (lane >= off) isc += t;
    }
    if (i < nb) blockOffs[i] = carry + isc - v;
    carry += __shfl(isc, 63, 64);
  }
}

__global__ __launch_bounds__(256) void gscan_emit_kernel(const int* __restrict__ arr,
                                                         const int* __restrict__ blockOffs,
                                                         int* __restrict__ out, int n) {
  __shared__ int ws[4];
  int tid = threadIdx.x, lane = tid & 63, wid = tid >> 6;
  int base = blockIdx.x * 2048 + tid * 8;
  int v[8];
  int s = 0;
  #pragma unroll
  for (int t = 0; t < 8; ++t) {
    int i = base + t;
    v[t] = (i < n) ? arr[i] : 0;
    s += v[t];
  }
  int isc = s;
  #pragma unroll
  for (int off = 1; off < 64; off <<= 1) {
    int t = __shfl_up(isc, off, 64);
    if (lane >= off) isc += t;
  }
  if (lane == 63) ws[wid] = isc;
  __syncthreads();
  int wb = 0;
  #pragma unroll
  for (int w = 0; w < 4; ++w)
    if (w < wid) wb += ws[w];
  int excl = blockOffs[blockIdx.x] + wb + isc - s;
  #pragma unroll
  for (int t = 0; t < 8; ++t) {
    int i = base + t;
    if (i < n) {
      out[i] = excl;
      excl += v[t];
    }
  }
}

// ---------- P3: scatter (src,dst) into bucket-sorted ebuf ----------
__global__ __launch_bounds__(256) void scatter_kernel(
    const int* __restrict__ idx_raw, const int* __restrict__ hdr,
    const int* __restrict__ O, unsigned long long* __restrict__ ebuf,
    int n_edges, int NC) {
  __shared__ int base[NBUCKP];
  const int c = blockIdx.x;
  for (int i = threadIdx.x; i < NBUCKP; i += 256) base[i] = O[(size_t)i * NC + c];
  __syncthreads();
  const int eb = c * CHUNK;
  const int lim = min(n_edges - eb, CHUNK);
  if (hdr[1]) {
    const uint4* sp = (const uint4*)(idx_raw + 2 * (size_t)eb);
    const uint4* dp = (const uint4*)(idx_raw + 2 * (size_t)n_edges + 2 * (size_t)eb);
    #pragma unroll
    for (int t = 0; t < CHUNK / 512; ++t) {
      int q = t * 256 + threadIdx.x;
      int e = 2 * q;
      if (e < lim) {
        uint4 sv = sp[q], dv = dp[q];
        int p0 = atomicAdd(&base[((int)dv.x) >> 7], 1);
        ebuf[p0] = (unsigned long long)sv.x | ((unsigned long long)dv.x << 32);
        if (e + 1 < lim) {
          int p1 = atomicAdd(&base[((int)dv.z) >> 7], 1);
          ebuf[p1] = (unsigned long long)sv.z | ((unsigned long long)dv.z << 32);
        }
      }
    }
  } else {
    const uint4* sp = (const uint4*)(idx_raw + (size_t)eb);
    const uint4* dp = (const uint4*)(idx_raw + (size_t)n_edges + eb);
    #pragma unroll
    for (int t = 0; t < CHUNK / 1024; ++t) {
      int q = t * 256 + threadIdx.x;
      int e = 4 * q;
      if (e < lim) {
        uint4 sv = sp[q], dv = dp[q];
        int p0 = atomicAdd(&base[((int)dv.x) >> 7], 1);
        ebuf[p0] = (unsigned long long)sv.x | ((unsigned long long)dv.x << 32);
        if (e + 1 < lim) {
          int p1 = atomicAdd(&base[((int)dv.y) >> 7], 1);
          ebuf[p1] = (unsigned long long)sv.y | ((unsigned long long)dv.y << 32);
        }
        if (e + 2 < lim) {
          int p2 = atomicAdd(&base[((int)dv.z) >> 7], 1);
          ebuf[p2] = (unsigned long long)sv.z | ((unsigned long long)dv.z << 32);
        }
        if (e + 3 < lim) {
          int p3 = atomicAdd(&base[((int)dv.w) >> 7], 1);
          ebuf[p3] = (unsigned long long)sv.w | ((unsigned long long)dv.w << 32);
        }
      }
    }
  }
}

// ---------- P4: per-bucket CSR finalize ----------
__global__ __launch_bounds__(256) void bucket_csr_kernel(
    const unsigned long long* __restrict__ ebuf, const int* __restrict__ O,
    int* __restrict__ col, int* __restrict__ row_start, float* __restrict__ deg_inv,
    int n_nodes, int n_edges, int NC) {
  __shared__ int cntl[128];
  __shared__ int cur[128];
  __shared__ int w0tot;
  const int b = blockIdx.x, tid = threadIdx.x;
  const int node0 = b << 7;
  const int beg = O[(size_t)b * NC];
  const int end = (b + 1 < NBUCKP) ? O[(size_t)(b + 1) * NC] : n_edges;
  if (tid < 128) cntl[tid] = 0;
  __syncthreads();
  for (int e = beg + tid; e < end; e += 256) {
    int d = (int)(ebuf[e] >> 32);
    atomicAdd(&cntl[d - node0], 1);
  }
  __syncthreads();
  int v = (tid < 128) ? cntl[tid] : 0;
  int lane = tid & 63;
  int isc = v;
  #pragma unroll
  for (int o = 1; o < 64; o <<= 1) {
    int t = __shfl_up(isc, o, 64);
    if (lane >= o) isc += t;
  }
  if (tid == 63) w0tot = isc;
  __syncthreads();
  int incl = isc + ((tid >= 64 && tid < 128) ? w0tot : 0);
  int excl = incl - v;
  if (tid < 128) {
    cur[tid] = excl;
    int node = node0 + tid;
    if (node < n_nodes) {
      row_start[node] = beg + excl;
      deg_inv[node] = 1.0f / (float)((v > 1) ? v : 1);
    }
  }
  __syncthreads();
  for (int e = beg + tid; e < end; e += 256) {
    unsigned long long u = ebuf[e];
    int s = (int)(u & 0xFFFFFFFFull);
    int d = (int)(u >> 32);
    int r = atomicAdd(&cur[d - node0], 1);  // LDS atomic
    col[beg + r] = s;
  }
  if (b == 0 && tid == 0) row_start[n_nodes] = n_edges;
}

// ---------- fused gather + MFMA concat-GEMM ----------
// Per block: 128 nodes. Phase A: 4 waves gather mean-agg rows of X into an
// LDS tile (bf16, row pad +8 -> 2-way LDS conflicts = free). Phase B: MFMA
// C = act([agg | X_self] @ [Wl|Wr]^T + b). KA = row feature count (64/128).
template <int KA, bool RELU, bool FINAL>
__global__ __launch_bounds__(256, 4) void fgemm_kernel(
    const unsigned short* __restrict__ Xconv, const void* __restrict__ Xraw,
    const int* __restrict__ row_start, const int* __restrict__ col,
    const float* __restrict__ deg_inv,
    const void* __restrict__ Wl_raw, const void* __restrict__ Wr_raw,
    const unsigned short* __restrict__ Wl_conv, const unsigned short* __restrict__ Wr_conv,
    const void* __restrict__ bias_raw, const int* __restrict__ hdr,
    unsigned short* __restrict__ Cb, void* __restrict__ Cf, int n_nodes) {
  constexpr int LROW = KA + 8;  // bf16 elems per LDS row (pad -> 2-way banks)
  __shared__ unsigned short tile[128 * LROW];
  const int tid = threadIdx.x;
  const int wave = tid >> 6, lane = tid & 63;
  const int hdr0 = hdr[0];
  const unsigned short* X  = hdr0 ? Xconv : (const unsigned short*)Xraw;
  const unsigned short* Wl = hdr0 ? Wl_conv : (const unsigned short*)Wl_raw;
  const unsigned short* Wr = hdr0 ? Wr_conv : (const unsigned short*)Wr_raw;
  const int nb = blockIdx.x * 128;

  // ---- Phase A: gather 32 nodes per wave ----
  if (KA == 128) {
    const int rg = lane >> 4, fq = lane & 15;  // 4 edge slots x 16 feature-quads
    for (int t = 0; t < 32; ++t) {
      const int n = nb + wave * 32 + t;
      float a[8];
      #pragma unroll
      for (int q = 0; q < 8; ++q) a[q] = 0.f;
      if (n < n_nodes) {
        int beg = row_start[n], end = row_start[n + 1];
        int i = beg;
        for (; i + 15 < end; i += 16) {
          int s0 = col[i + rg], s1 = col[i + 4 + rg], s2 = col[i + 8 + rg], s3 = col[i + 12 + rg];
          uint4 p0 = *(const uint4*)(X + (size_t)s0 * 128 + fq * 8);
          uint4 p1 = *(const uint4*)(X + (size_t)s1 * 128 + fq * 8);
          uint4 p2 = *(const uint4*)(X + (size_t)s2 * 128 + fq * 8);
          uint4 p3 = *(const uint4*)(X + (size_t)s3 * 128 + fq * 8);
          acc8(a, p0); acc8(a, p1); acc8(a, p2); acc8(a, p3);
        }
        for (; i + 3 < end; i += 4) {
          uint4 p0 = *(const uint4*)(X + (size_t)col[i + rg] * 128 + fq * 8);
          acc8(a, p0);
        }
        if (i + rg < end) {
          uint4 p0 = *(const uint4*)(X + (size_t)col[i + rg] * 128 + fq * 8);
          acc8(a, p0);
        }
        #pragma unroll
        for (int m = 16; m < 64; m <<= 1)
          #pragma unroll
          for (int q = 0; q < 8; ++q) a[q] += __shfl_xor(a[q], m, 64);
      }
      if (rg == 0) {
        float di = (n < n_nodes) ? deg_inv[n] : 0.f;
        uint4 o;
        o.x = pack2(a[0] * di, a[1] * di);
        o.y = pack2(a[2] * di, a[3] * di);
        o.z = pack2(a[4] * di, a[5] * di);
        o.w = pack2(a[6] * di, a[7] * di);
        *(uint4*)&tile[(wave * 32 + t) * LROW + fq * 8] = o;
      }
    }
  } else {  // KA == 64: 2 nodes per pass (two 32-lane halves)
    const int half = lane >> 5, l32 = lane & 31;
    const int rg = l32 >> 3, fq = l32 & 7;  // 4 edge slots x 8 feature-quads
    for (int t = 0; t < 16; ++t) {
      const int n = nb + wave * 32 + t * 2 + half;
      float a[8];
      #pragma unroll
      for (int q = 0; q < 8; ++q) a[q] = 0.f;
      if (n < n_nodes) {
        int beg = row_start[n], end = row_start[n + 1];
        int i = beg;
        for (; i + 15 < end; i += 16) {
          int s0 = col[i + rg], s1 = col[i + 4 + rg], s2 = col[i + 8 + rg], s3 = col[i + 12 + rg];
          uint4 p0 = *(const uint4*)(X + (size_t)s0 * 64 + fq * 8);
          uint4 p1 = *(const uint4*)(X + (size_t)s1 * 64 + fq * 8);
          uint4 p2 = *(const uint4*)(X + (size_t)s2 * 64 + fq * 8);
          uint4 p3 = *(const uint4*)(X + (size_t)s3 * 64 + fq * 8);
          acc8(a, p0); acc8(a, p1); acc8(a, p2); acc8(a, p3);
        }
        for (; i + 3 < end; i += 4) {
          uint4 p0 = *(const uint4*)(X + (size_t)col[i + rg] * 64 + fq * 8);
          acc8(a, p0);
        }
        if (i + rg < end) {
          uint4 p0 = *(const uint4*)(X + (size_t)col[i + rg] * 64 + fq * 8);
          acc8(a, p0);
        }
        #pragma unroll
        for (int m = 8; m <= 16; m <<= 1)
          #pragma unroll
          for (int q = 0; q < 8; ++q) a[q] += __shfl_xor(a[q], m, 64);
      }
      if (rg == 0) {
        float di = (n < n_nodes) ? deg_inv[n] : 0.f;
        uint4 o;
        o.x = pack2(a[0] * di, a[1] * di);
        o.y = pack2(a[2] * di, a[3] * di);
        o.z = pack2(a[4] * di, a[5] * di);
        o.w = pack2(a[6] * di, a[7] * di);
        *(uint4*)&tile[(wave * 32 + t * 2 + half) * LROW + fq * 8] = o;
      }
    }
  }
  __syncthreads();

  // ---- Phase B: MFMA ----
  const int m16 = lane & 15, quad = lane >> 4;
  const int gnb = nb + wave * 32, lnb = wave * 32;
  int srow0 = gnb + m16;      if (srow0 >= n_nodes) srow0 = n_nodes - 1;
  int srow1 = gnb + 16 + m16; if (srow1 >= n_nodes) srow1 = n_nodes - 1;

  f32x4 acc[2][8];
  #pragma unroll
  for (int mi = 0; mi < 2; ++mi)
    #pragma unroll
    for (int ji = 0; ji < 8; ++ji) acc[mi][ji] = (f32x4){0.f, 0.f, 0.f, 0.f};

  constexpr int NSTEP = (2 * KA) / 32;
  #pragma unroll
  for (int c = 0; c < NSTEP; ++c) {
    const bool first = (c * 32) < KA;
    const int kb = first ? c * 32 : c * 32 - KA;
    const int ko = kb + quad * 8;
    bf16x8 a0, a1;
    if (first) {  // agg operand from LDS
      a0 = *(const bf16x8*)&tile[(lnb + m16) * LROW + ko];
      a1 = *(const bf16x8*)&tile[(lnb + 16 + m16) * LROW + ko];
    } else {      // self operand from global
      a0 = *(const bf16x8*)(X + (size_t)srow0 * KA + ko);
      a1 = *(const bf16x8*)(X + (size_t)srow1 * KA + ko);
    }
    const unsigned short* W = first ? Wl : Wr;
    bf16x8 w[8];
    #pragma unroll
    for (int ji = 0; ji < 8; ++ji)
      w[ji] = *(const bf16x8*)(W + (size_t)(ji * 16 + m16) * KA + ko);
    #pragma unroll
    for (int ji = 0; ji < 8; ++ji) {
      acc[0][ji] = __builtin_amdgcn_mfma_f32_16x16x32_bf16(a0, w[ji], acc[0][ji], 0, 0, 0);
      acc[1][ji] = __builtin_amdgcn_mfma_f32_16x16x32_bf16(a1, w[ji], acc[1][ji], 0, 0, 0);
    }
  }

  const bool f32out = FINAL && (hdr0 == 1);
  #pragma unroll
  for (int ji = 0; ji < 8; ++ji) {
    int j = ji * 16 + m16;
    float bj = hdr0 ? ((const float*)bias_raw)[j] : b2f(((const unsigned short*)bias_raw)[j]);
    #pragma unroll
    for (int mi = 0; mi < 2; ++mi) {
      #pragma unroll
      for (int r = 0; r < 4; ++r) {
        int n = gnb + mi * 16 + quad * 4 + r;
        if (n >= n_nodes) continue;
        float v = acc[mi][ji][r] + bj;
        if (RELU) v = fmaxf(v, 0.f);
        if (FINAL) {
          if (f32out) ((float*)Cf)[(size_t)n * 128 + j] = v;
          else ((unsigned short*)Cf)[(size_t)n * 128 + j] = f2b(v);
        } else {
          Cb[(size_t)n * 128 + j] = f2b(v);
        }
      }
    }
  }
}

// ---------- launch ----------
extern "C" void kernel_launch(void* const* d_in, const int* in_sizes, int n_in,
                              void* d_out, int out_size, void* d_ws, size_t ws_size,
                              hipStream_t stream) {
  const void* x_raw  = d_in[0];
  const int* idx_raw = (const int*)d_in[1];
  const void* W1l = d_in[2];
  const void* b1  = d_in[3];
  const void* W1r = d_in[4];
  const void* W2l = d_in[5];
  const void* b2  = d_in[6];
  const void* W2r = d_in[7];
  const int N = in_sizes[0] / 64;
  const int E = in_sizes[1] / 2;
  const int NC = (E + CHUNK - 1) / CHUNK;
  const int NSCAN = NBUCKP * NC;
  const int NBs = (NSCAN + 2047) / 2048;
  const int NBUCK = (N + 127) >> 7;

  char* ws = (char*)d_ws;
  size_t off = 0;
  auto alloc = [&](size_t bytes) {
    char* p = ws + off;
    off = (off + bytes + 511) & ~((size_t)511);
    return p;
  };
  int* hdr        = (int*)alloc(512);
  int* H          = (int*)alloc((size_t)NSCAN * 4);
  int* O          = (int*)alloc((size_t)NSCAN * 4);
  int* blockSums  = (int*)alloc((size_t)NBs * 4);
  int* blockOffs  = (int*)alloc((size_t)NBs * 4);
  unsigned long long* ebuf = (unsigned long long*)alloc((size_t)E * 8);
  int* col        = (int*)alloc((size_t)E * 4);
  int* row_start  = (int*)alloc(((size_t)N + 1) * 4);
  float* deg_inv  = (float*)alloc((size_t)N * 4);
  unsigned short* W1l_h = (unsigned short*)alloc(16384);
  unsigned short* W1r_h = (unsigned short*)alloc(16384);
  unsigned short* W2l_h = (unsigned short*)alloc(32768);
  unsigned short* W2r_h = (unsigned short*)alloc(32768);
  unsigned short* xc   = (unsigned short*)alloc((size_t)N * 64 * 2);
  unsigned short* hbuf = (unsigned short*)alloc((size_t)N * 128 * 2);

  detect_kernel<<<1, 64, 0, stream>>>(x_raw, idx_raw, hdr);
  convert_w_kernel<<<(49152 + 255) / 256, 256, 0, stream>>>(
      W1l, W1r, W2l, W2r, hdr, W1l_h, W1r_h, W2l_h, W2r_h);
  convert_x_kernel<<<(N * 64 + 255) / 256, 256, 0, stream>>>(x_raw, hdr, xc, N * 64);
  hist_chunks_kernel<<<NC, 256, 0, stream>>>(idx_raw, hdr, H, E, NC);
  gscan_sums_kernel<<<NBs, 256, 0, stream>>>(H, blockSums, NSCAN);
  gscan_offsets_kernel<<<1, 64, 0, stream>>>(blockSums, blockOffs, NBs);
  gscan_emit_kernel<<<NBs, 256, 0, stream>>>(H, blockOffs, O, NSCAN);
  scatter_kernel<<<NC, 256, 0, stream>>>(idx_raw, hdr, O, ebuf, E, NC);
  bucket_csr_kernel<<<NBUCK, 256, 0, stream>>>(ebuf, O, col, row_start, deg_inv, N, E, NC);
  fgemm_kernel<64, true, false><<<(N + 127) / 128, 256, 0, stream>>>(
      xc, x_raw, row_start, col, deg_inv, W1l, W1r, W1l_h, W1r_h, b1, hdr,
      hbuf, nullptr, N);
  fgemm_kernel<128, false, true><<<(N + 127) / 128, 256, 0, stream>>>(
      hbuf, hbuf, row_start, col, deg_inv, W2l, W2r, W2l_h, W2r_h, b2, hdr,
      nullptr, d_out, N);
}